// Round 9
// baseline (360.374 us; speedup 1.0000x reference)
//
#include <hip/hip_runtime.h>
#include <hip/hip_bf16.h>
#include <stdint.h>

typedef __attribute__((ext_vector_type(8))) short short8;
typedef __attribute__((ext_vector_type(4))) float floatx4;

// Q pre-scale: 0.125 (1/sqrt(K)) * log2(e), so exp(s/8) == exp2(q'.k)
#define QSCALE 0.18033688f

__device__ __forceinline__ unsigned short f2bf(float f) {
    unsigned int u = __float_as_uint(f);
    u += 0x7fffu + ((u >> 16) & 1u);
    return (unsigned short)(u >> 16);
}
__device__ __forceinline__ unsigned int pack2bf(float a, float b) {
    __hip_bfloat162 h = __float22bfloat162_rn(make_float2(a, b));
    return *reinterpret_cast<unsigned int*>(&h);
}

// async global->LDS, 16B per lane; LDS dst must be wave-uniform base + lane*16
__device__ __forceinline__ void async16(const void* g, void* l) {
    __builtin_amdgcn_global_load_lds(
        (const __attribute__((address_space(1))) unsigned int*)g,
        (__attribute__((address_space(3))) unsigned int*)l, 16, 0, 0);
}

// ---------------------------------------------------------------------------
// prep: fused cvt_bf16(x) + tcvt(wqkv). Blocks [0,4096) convert x fp32->bf16
// (8 elem/thread); blocks [4096,4864) transpose-convert wqkv into wqkvT.
// Independent memory-bound work -> one launch, natural overlap.
// ---------------------------------------------------------------------------
__global__ __launch_bounds__(256) void prep(const float* __restrict__ x,
                                            const float* __restrict__ wqkv,
                                            unsigned short* __restrict__ xb,
                                            unsigned short* __restrict__ wqkvT) {
    __shared__ unsigned short t[64][72];
    const int bid = blockIdx.x, tid = threadIdx.x;
    if (bid < 4096) {
        int i = bid * 256 + tid;
        const float4 a = ((const float4*)x)[2 * i];
        const float4 b = ((const float4*)x)[2 * i + 1];
        ushort4 lo, hi;
        lo.x = f2bf(a.x); lo.y = f2bf(a.y); lo.z = f2bf(a.z); lo.w = f2bf(a.w);
        hi.x = f2bf(b.x); hi.y = f2bf(b.y); hi.z = f2bf(b.z); hi.w = f2bf(b.w);
        ((ushort4*)xb)[2 * i] = lo;
        ((ushort4*)xb)[2 * i + 1] = hi;
        return;
    }
    // tcvt wqkv: [1024][3072] -> wqkvT [3072][1024]
    const int id = bid - 4096;
    const int c0 = (id % 48) * 64, r0 = (id / 48) * 64;
    const int R = 1024, C = 3072;
    #pragma unroll
    for (int it = 0; it < 4; it++) {
        int idx = it * 256 + tid;
        int rr = idx >> 4, cc = (idx & 15) * 4;
        float4 v = *(const float4*)(wqkv + (size_t)(r0 + rr) * C + c0 + cc);
        t[cc + 0][rr] = f2bf(v.x);
        t[cc + 1][rr] = f2bf(v.y);
        t[cc + 2][rr] = f2bf(v.z);
        t[cc + 3][rr] = f2bf(v.w);
    }
    __syncthreads();
    #pragma unroll
    for (int it = 0; it < 2; it++) {
        int idx = it * 256 + tid;
        int cc = idx >> 3, r8 = (idx & 7) * 8;
        short8 v = *(const short8*)&t[cc][r8];
        *(short8*)(wqkvT + (size_t)(c0 + cc) * R + r0 + r8) = v;
    }
}

// ---------------------------------------------------------------------------
// tcvt: fp32 [R][C] -> bf16 [C][R]  (64x64 tiles via LDS) — used for wo only
// (woT overlays drpT, which is live until attn_pv completes, so this cannot
// be fused earlier).
// ---------------------------------------------------------------------------
__global__ __launch_bounds__(256) void tcvt(const float* __restrict__ src,
                                            unsigned short* __restrict__ dst, int R, int C) {
    __shared__ unsigned short t[64][72];
    const int tid = threadIdx.x;
    const int r0 = blockIdx.y * 64, c0 = blockIdx.x * 64;
    #pragma unroll
    for (int it = 0; it < 4; it++) {
        int idx = it * 256 + tid;
        int rr = idx >> 4, cc = (idx & 15) * 4;
        float4 v = *(const float4*)(src + (size_t)(r0 + rr) * C + c0 + cc);
        t[cc + 0][rr] = f2bf(v.x);
        t[cc + 1][rr] = f2bf(v.y);
        t[cc + 2][rr] = f2bf(v.z);
        t[cc + 3][rr] = f2bf(v.w);
    }
    __syncthreads();
    #pragma unroll
    for (int it = 0; it < 2; it++) {
        int idx = it * 256 + tid;
        int cc = idx >> 3, r8 = (idx & 7) * 8;
        short8 v = *(const short8*)&t[cc][r8];
        *(short8*)(dst + (size_t)(c0 + cc) * R + r0 + r8) = v;
    }
}

// ---------------------------------------------------------------------------
// qkv_gemm (R5-proven: 128x128 tile, BK=32, 2-barrier, dim3 grid).
// ---------------------------------------------------------------------------
__global__ __launch_bounds__(256) void qkv_gemm(
    const unsigned short* __restrict__ A, const unsigned short* __restrict__ Bt,
    unsigned short* __restrict__ qb, unsigned short* __restrict__ kb,
    unsigned short* __restrict__ vb)
{
    __shared__ __align__(16) unsigned short As[128 * 32];
    __shared__ __align__(16) unsigned short Bs[128 * 32];
    const int tid = threadIdx.x, wave = tid >> 6, lane = tid & 63;
    const int quad = lane >> 4, lr = lane & 15;
    const int wr = wave >> 1, wc = wave & 1;
    const int bm = blockIdx.y * 128, bn = blockIdx.x * 128;
    const int lrow = lane >> 2, lcol = (lane & 3) * 8;

    floatx4 acc[4][4];
    #pragma unroll
    for (int i = 0; i < 4; i++)
        #pragma unroll
        for (int j = 0; j < 4; j++) acc[i][j] = (floatx4)0.0f;

    for (int k0 = 0; k0 < 1024; k0 += 32) {
        #pragma unroll
        for (int t = 0; t < 2; t++) {
            const int rbase = wave * 32 + t * 16;       // wave-uniform
            const int r = rbase + lrow;
            async16(A  + (size_t)(bm + r) * 1024 + k0 + lcol, &As[rbase * 32]);
            async16(Bt + (size_t)(bn + r) * 1024 + k0 + lcol, &Bs[rbase * 32]);
        }
        __syncthreads();
        short8 af[4], bfr[4];
        #pragma unroll
        for (int i = 0; i < 4; i++)
            af[i] = *(const short8*)&As[(wr * 64 + i * 16 + lr) * 32 + quad * 8];
        #pragma unroll
        for (int j = 0; j < 4; j++)
            bfr[j] = *(const short8*)&Bs[(wc * 64 + j * 16 + lr) * 32 + quad * 8];
        #pragma unroll
        for (int i = 0; i < 4; i++)
            #pragma unroll
            for (int j = 0; j < 4; j++)
                acc[i][j] = __builtin_amdgcn_mfma_f32_16x16x32_bf16(af[i], bfr[j], acc[i][j], 0, 0, 0);
        __syncthreads();
    }

    const int part = bn >> 10;
    unsigned short* __restrict__ dstb = (part == 0) ? qb : ((part == 1) ? kb : vb);
    const float sc = (part == 0) ? QSCALE : 1.0f;
    const int dbase = bn & 1023;
    #pragma unroll
    for (int i = 0; i < 4; i++)
        #pragma unroll
        for (int j = 0; j < 4; j++)
            #pragma unroll
            for (int r = 0; r < 4; r++) {
                int row = bm + wr * 64 + i * 16 + quad * 4 + r;
                int d   = dbase + wc * 64 + j * 16 + lr;
                int b = row >> 11, l = row & 2047;
                int flat = (l << 10) | d;
                int h = flat >> 17;
                int rem = flat & 131071;
                int l2 = rem >> 6, kk = rem & 63;
                dstb[((size_t)(b * 16 + h) * 2048 + l2) * 64 + kk] = f2bf(acc[i][j][r] * sc);
            }
}

__global__ __launch_bounds__(256) void out_gemm(
    const unsigned short* __restrict__ A, const unsigned short* __restrict__ Bt,
    float* __restrict__ C)
{
    __shared__ __align__(16) unsigned short As[128 * 32];
    __shared__ __align__(16) unsigned short Bs[128 * 32];
    const int tid = threadIdx.x, wave = tid >> 6, lane = tid & 63;
    const int quad = lane >> 4, lr = lane & 15;
    const int wr = wave >> 1, wc = wave & 1;
    const int bm = blockIdx.y * 128, bn = blockIdx.x * 128;
    const int lrow = lane >> 2, lcol = (lane & 3) * 8;

    floatx4 acc[4][4];
    #pragma unroll
    for (int i = 0; i < 4; i++)
        #pragma unroll
        for (int j = 0; j < 4; j++) acc[i][j] = (floatx4)0.0f;

    for (int k0 = 0; k0 < 1024; k0 += 32) {
        #pragma unroll
        for (int t = 0; t < 2; t++) {
            const int rbase = wave * 32 + t * 16;
            const int r = rbase + lrow;
            async16(A  + (size_t)(bm + r) * 1024 + k0 + lcol, &As[rbase * 32]);
            async16(Bt + (size_t)(bn + r) * 1024 + k0 + lcol, &Bs[rbase * 32]);
        }
        __syncthreads();
        short8 af[4], bfr[4];
        #pragma unroll
        for (int i = 0; i < 4; i++)
            af[i] = *(const short8*)&As[(wr * 64 + i * 16 + lr) * 32 + quad * 8];
        #pragma unroll
        for (int j = 0; j < 4; j++)
            bfr[j] = *(const short8*)&Bs[(wc * 64 + j * 16 + lr) * 32 + quad * 8];
        #pragma unroll
        for (int i = 0; i < 4; i++)
            #pragma unroll
            for (int j = 0; j < 4; j++)
                acc[i][j] = __builtin_amdgcn_mfma_f32_16x16x32_bf16(af[i], bfr[j], acc[i][j], 0, 0, 0);
        __syncthreads();
    }
    #pragma unroll
    for (int i = 0; i < 4; i++)
        #pragma unroll
        for (int j = 0; j < 4; j++)
            #pragma unroll
            for (int r = 0; r < 4; r++) {
                int row = bm + wr * 64 + i * 16 + quad * 4 + r;
                int col = bn + wc * 64 + j * 16 + lr;
                C[(size_t)row * 1024 + col] = acc[i][j][r];
            }
}

// ---------------------------------------------------------------------------
// vtrans_denom: fused vtrans (blocks [0,2048)) + attn_denom v2 (blocks
// [2048,6144)). Both depend only on qkv_gemm; vtrans's pure-memory blocks
// drain under denom's compute-bound blocks instead of a serial launch.
// Denom body is the R5-verified v2 verbatim (Q/K double-buffered LDS,
// global_load_lds staging, rule-21 involution, one barrier per head).
// LDS 32 KB -> 5 blocks/CU; vtrans path aliases the first 9 KB.
// ---------------------------------------------------------------------------
__global__ __launch_bounds__(256, 5) void vtrans_denom(
    const unsigned short* __restrict__ qb, const unsigned short* __restrict__ kb,
    const unsigned short* __restrict__ vb, unsigned short* __restrict__ vbt,
    unsigned short* __restrict__ drpT)
{
    __shared__ __align__(16) unsigned short Qs[2][64 * 64];  // 16 KB
    __shared__ __align__(16) unsigned short Ks[2][64 * 64];  // 16 KB
    const int bid = blockIdx.x, tid = threadIdx.x;

    if (bid < 2048) {
        // ---- vtrans path: vb[bh][2048][64] -> vbt[bh][64][2048], 64x64 tile ----
        unsigned short (*t)[72] = (unsigned short (*)[72])&Qs[0][0];  // 9 KB alias
        const int bh = bid >> 5, m0 = (bid & 31) * 64;
        const unsigned short* src = vb + ((size_t)bh * 2048 + m0) * 64;
        unsigned short* dst = vbt + ((size_t)bh << 17) + m0;
        union { short8 v; unsigned short u[8]; } tmp;
        #pragma unroll
        for (int it = 0; it < 2; it++) {
            int idx = it * 256 + tid;
            int m = idx >> 3, c8 = (idx & 7) * 8;
            tmp.v = *(const short8*)(src + (size_t)m * 64 + c8);
            #pragma unroll
            for (int j = 0; j < 8; j++) t[c8 + j][m] = tmp.u[j];
        }
        __syncthreads();
        #pragma unroll
        for (int it = 0; it < 2; it++) {
            int idx = it * 256 + tid;
            int k = idx >> 3, c8 = (idx & 7) * 8;
            short8 v = *(const short8*)&t[k][c8];
            *(short8*)(dst + (size_t)k * 2048 + c8) = v;
        }
        return;
    }

    // ---- attn_denom v2 path ----
    const int id = bid - 2048;
    const int M0 = (id & 31) * 64, L0 = ((id >> 5) & 31) * 64, b = id >> 10;
    const int wave = tid >> 6, lane = tid & 63;
    const int quad = lane >> 4, lr = lane & 15;
    const int e7 = lr & 7;

    const int klr = lane >> 3;
    const int ksw8 = ((lane & 7) ^ klr) * 8;
    const size_t hb0 = ((size_t)(b * 16)) << 17;
    const unsigned short* qsrc0 = qb + hb0 + (size_t)(L0 + wave * 8 + klr) * 64 + ksw8;
    const unsigned short* ksrc0 = kb + hb0 + (size_t)(M0 + wave * 8 + klr) * 64 + ksw8;

    floatx4 e[4];
    #pragma unroll
    for (int i = 0; i < 4; i++) e[i] = (floatx4)0.0f;

    async16(qsrc0,           &Qs[0][(wave * 8) * 64]);
    async16(qsrc0 + 32 * 64, &Qs[0][(32 + wave * 8) * 64]);
    async16(ksrc0,           &Ks[0][(wave * 8) * 64]);
    async16(ksrc0 + 32 * 64, &Ks[0][(32 + wave * 8) * 64]);
    __syncthreads();

    for (int h = 0; h < 16; h++) {
        const int cur = h & 1, nxt = cur ^ 1;
        if (h < 15) {
            const unsigned short* qs = qsrc0 + ((size_t)(h + 1) << 17);
            const unsigned short* ks = ksrc0 + ((size_t)(h + 1) << 17);
            async16(qs,           &Qs[nxt][(wave * 8) * 64]);
            async16(qs + 32 * 64, &Qs[nxt][(32 + wave * 8) * 64]);
            async16(ks,           &Ks[nxt][(wave * 8) * 64]);
            async16(ks + 32 * 64, &Ks[nxt][(32 + wave * 8) * 64]);
        }
        const unsigned short* qsp = &Qs[cur][0];
        const unsigned short* ksp = &Ks[cur][0];
        const int rq = wave * 16 + lr;
        short8 qf0 = *(const short8*)&qsp[rq * 64 + (quad ^ e7) * 8];
        short8 qf1 = *(const short8*)&qsp[rq * 64 + ((4 + quad) ^ e7) * 8];
        #pragma unroll
        for (int mt = 0; mt < 4; mt++) {
            const int rk = mt * 16 + lr;
            short8 kf0 = *(const short8*)&ksp[rk * 64 + (quad ^ e7) * 8];
            short8 kf1 = *(const short8*)&ksp[rk * 64 + ((4 + quad) ^ e7) * 8];
            floatx4 s = (floatx4)0.0f;
            __builtin_amdgcn_s_setprio(1);
            s = __builtin_amdgcn_mfma_f32_16x16x32_bf16(kf0, qf0, s, 0, 0, 0);
            s = __builtin_amdgcn_mfma_f32_16x16x32_bf16(kf1, qf1, s, 0, 0, 0);
            __builtin_amdgcn_s_setprio(0);
            e[mt][0] += __builtin_amdgcn_exp2f(s[0]);
            e[mt][1] += __builtin_amdgcn_exp2f(s[1]);
            e[mt][2] += __builtin_amdgcn_exp2f(s[2]);
            e[mt][3] += __builtin_amdgcn_exp2f(s[3]);
        }
        if (h < 15) __syncthreads();
    }
    #pragma unroll
    for (int mt = 0; mt < 4; mt++) {
        float r0 = __builtin_amdgcn_rcpf(e[mt][0]);
        float r1 = __builtin_amdgcn_rcpf(e[mt][1]);
        float r2 = __builtin_amdgcn_rcpf(e[mt][2]);
        float r3 = __builtin_amdgcn_rcpf(e[mt][3]);
        uint2 o;
        o.x = pack2bf(r0, r1);
        o.y = pack2bf(r2, r3);
        int mtg = (M0 >> 4) + mt;
        int ltg = (L0 >> 4) + wave;
        *(uint2*)(drpT + ((((size_t)b * 128 + mtg) * 128 + ltg) << 8) + lane * 4) = o;
    }
}

// ---------------------------------------------------------------------------
// attn_pv v6 (R5, verbatim — measured 111 us): 3-buffer K/V rotation, full
// Ps[128][64], drp reload post-S.
// ---------------------------------------------------------------------------
__global__ __launch_bounds__(256, 4) void attn_pv(
    const unsigned short* __restrict__ qb, const unsigned short* __restrict__ kb,
    const unsigned short* __restrict__ vbt, const unsigned short* __restrict__ drpT,
    unsigned short* __restrict__ cb)
{
    __shared__ __align__(16) unsigned short KV[3][64 * 64];  // 24 KB rotating K/V
    __shared__ __align__(16) unsigned short Ps[128 * 64];    // 16 KB
    const int tid = threadIdx.x, wave = tid >> 6, lane = tid & 63;
    const int quad = lane >> 4, lr = lane & 15;
    const int e7 = lr & 7;
    const int flat = blockIdx.x;
    const int swz = (flat & 7) * 128 + (flat >> 3);
    const int Lt = swz & 15;
    const int h = (swz >> 4) & 15;
    const int b = swz >> 8;
    const int L0 = Lt * 128;
    const size_t head = (size_t)(b * 16 + h);
    const unsigned short* qbase = qb + (head << 17);
    const unsigned short* kbase = kb + (head << 17);
    const unsigned short* vtb   = vbt + (head << 17);        // [64][2048]
    const unsigned short* dbase = drpT + (((size_t)b * 128 * 128 + (L0 >> 4) + wave * 2) << 8) + lane * 4;

    const int klr = lane >> 3;
    const int ksw = (lane & 7) ^ klr;
    const unsigned short* ksrc0 = kbase + (size_t)(wave * 8 + klr) * 64 + ksw * 8;
    const unsigned short* vsrc0 = vtb + (size_t)(wave * 8 + klr) * 2048 + ksw * 8;

    short8 qf[2][2];
    #pragma unroll
    for (int j = 0; j < 2; j++) {
        const unsigned short* qr = qbase + (size_t)(L0 + wave * 32 + j * 16 + lr) * 64;
        qf[j][0] = *(const short8*)(qr + quad * 8);
        qf[j][1] = *(const short8*)(qr + 32 + quad * 8);
    }

    floatx4 oacc[2][4];
    #pragma unroll
    for (int i = 0; i < 2; i++)
        #pragma unroll
        for (int j = 0; j < 4; j++) oacc[i][j] = (floatx4)0.0f;

    async16(ksrc0,             &KV[0][(wave * 8) * 64]);
    async16(ksrc0 + 32 * 64,   &KV[0][(32 + wave * 8) * 64]);
    async16(vsrc0,             &KV[1][(wave * 8) * 64]);
    async16(vsrc0 + 32 * 2048, &KV[1][(32 + wave * 8) * 64]);
    uint2 du[4][2];
    #pragma unroll
    for (int mt = 0; mt < 4; mt++)
        #pragma unroll
        for (int j = 0; j < 2; j++)
            du[mt][j] = *(const uint2*)(dbase + ((size_t)mt << 15) + (j << 8));
    __syncthreads();

    int kcur = 0, vcur = 1, sp = 2;
    for (int t = 0; t < 32; t++) {
        const int M0 = t * 64;
        if (t < 31) {
            const unsigned short* ks = ksrc0 + (size_t)(M0 + 64) * 64;
            async16(ks,           &KV[sp][(wave * 8) * 64]);
            async16(ks + 32 * 64, &KV[sp][(32 + wave * 8) * 64]);
        }
        const unsigned short* ksp = &KV[kcur][0];
        #pragma unroll
        for (int mt = 0; mt < 4; mt++) {
            const int rk = mt * 16 + lr;
            short8 kf0 = *(const short8*)&ksp[rk * 64 + (quad ^ e7) * 8];
            short8 kf1 = *(const short8*)&ksp[rk * 64 + ((4 + quad) ^ e7) * 8];
            #pragma unroll
            for (int j = 0; j < 2; j++) {
                uint2 duv = du[mt][j];
                floatx4 s = (floatx4)0.0f;
                __builtin_amdgcn_s_setprio(1);
                s = __builtin_amdgcn_mfma_f32_16x16x32_bf16(kf0, qf[j][0], s, 0, 0, 0);
                s = __builtin_amdgcn_mfma_f32_16x16x32_bf16(kf1, qf[j][1], s, 0, 0, 0);
                __builtin_amdgcn_s_setprio(0);
                float r0 = __uint_as_float(duv.x << 16);
                float r1 = __uint_as_float(duv.x & 0xffff0000u);
                float r2 = __uint_as_float(duv.y << 16);
                float r3 = __uint_as_float(duv.y & 0xffff0000u);
                float p0 = __builtin_amdgcn_exp2f(s[0]) * r0;
                float p1 = __builtin_amdgcn_exp2f(s[1]) * r1;
                float p2 = __builtin_amdgcn_exp2f(s[2]) * r2;
                float p3 = __builtin_amdgcn_exp2f(s[3]) * r3;
                uint2 o;
                o.x = pack2bf(p0, p1);
                o.y = pack2bf(p2, p3);
                const int l_loc = wave * 32 + j * 16 + lr;
                const int lb16 = mt * 2 + (quad >> 1);
                *(uint2*)&Ps[l_loc * 64 + (lb16 ^ e7) * 8 + (quad & 1) * 4] = o;
            }
        }
        if (t < 31) {
            __syncthreads();
            const unsigned short* vs = vsrc0 + (M0 + 64);
            async16(vs,             &KV[kcur][(wave * 8) * 64]);
            async16(vs + 32 * 2048, &KV[kcur][(32 + wave * 8) * 64]);
            #pragma unroll
            for (int mt = 0; mt < 4; mt++)
                #pragma unroll
                for (int j = 0; j < 2; j++)
                    du[mt][j] = *(const uint2*)(dbase + (((size_t)((t + 1) * 4 + mt)) << 15) + (j << 8));
        }
        __builtin_amdgcn_sched_barrier(0);
        const unsigned short* vsp = &KV[vcur][0];
        #pragma unroll
        for (int f = 0; f < 2; f++) {
            short8 pf[2], vf[4];
            #pragma unroll
            for (int i2 = 0; i2 < 2; i2++)
                pf[i2] = *(const short8*)&Ps[(wave * 32 + i2 * 16 + lr) * 64 + ((f * 4 + quad) ^ e7) * 8];
            #pragma unroll
            for (int j2 = 0; j2 < 4; j2++) {
                const int rv = j2 * 16 + lr;
                vf[j2] = *(const short8*)&vsp[rv * 64 + ((f * 4 + quad) ^ e7) * 8];
            }
            __builtin_amdgcn_s_setprio(1);
            #pragma unroll
            for (int j2 = 0; j2 < 4; j2++)
                #pragma unroll
                for (int i2 = 0; i2 < 2; i2++)
                    oacc[i2][j2] = __builtin_amdgcn_mfma_f32_16x16x32_bf16(
                        pf[i2], vf[j2], oacc[i2][j2], 0, 0, 0);
            __builtin_amdgcn_s_setprio(0);
        }
        if (t < 31) {
            __syncthreads();
            const int ok = kcur;
            kcur = sp;
            sp = vcur;
            vcur = ok;
        }
    }
    #pragma unroll
    for (int i2 = 0; i2 < 2; i2++)
        #pragma unroll
        for (int j2 = 0; j2 < 4; j2++)
            #pragma unroll
            for (int r = 0; r < 4; r++) {
                int row = L0 + wave * 32 + i2 * 16 + quad * 4 + r;
                int col = h * 64 + j2 * 16 + lr;
                cb[(size_t)(b * 2048 + row) * 1024 + col] = f2bf(oacc[i2][j2][r]);
            }
}

extern "C" void kernel_launch(void* const* d_in, const int* in_sizes, int n_in,
                              void* d_out, int out_size, void* d_ws, size_t ws_size,
                              hipStream_t stream) {
    const float* x    = (const float*)d_in[0];   // [4,2048,1024]
    const float* wqkv = (const float*)d_in[1];   // [1024,3072]
    const float* wo   = (const float*)d_in[2];   // [1024,1024]
    float* out = (float*)d_out;                  // [4,2048,1024] fp32

    // workspace: 100,663,296 bytes with overlays
    unsigned short* W = (unsigned short*)d_ws;
    unsigned short* qb   = W;                    // [4,16,2048,64] pre-scaled Q
    unsigned short* kb   = W + 8388608;          // [4,16,2048,64]
    unsigned short* vbt  = W + 16777216;         // [4,16,64,2048] V^T
    unsigned short* drpT = W + 25165824;         // [4][128mt][128lt][256] recip denom
    unsigned short* cb   = W + 41943040;         // [8192,1024] concat
    // overlays (lifetime-disjoint):
    unsigned short* xb    = drpT;                // bf16 x   (dead before denom)
    unsigned short* wqkvT = drpT + 8388608;      // bf16 wqkv^T [3072][1024]
    unsigned short* vb    = cb;                  // V row-major (dead before pv)
    unsigned short* woT   = drpT;                // bf16 wo^T [1024][1024] (after pv)

    prep        <<<4864, 256, 0, stream>>>(x, wqkv, xb, wqkvT);
    qkv_gemm    <<<dim3(24, 64), 256, 0, stream>>>(xb, wqkvT, qb, kb, vb);
    vtrans_denom<<<6144, 256, 0, stream>>>(qb, kb, vb, vbt, drpT);
    attn_pv     <<<1024, 256, 0, stream>>>(qb, kb, vbt, drpT, cb);
    tcvt        <<<dim3(16, 16), 256, 0, stream>>>(wo, woT, 1024, 1024);
    out_gemm    <<<dim3(8, 64), 256, 0, stream>>>(cb, woT, out);
}

// Round 10
// 352.641 us; speedup vs baseline: 1.0219x; 1.0219x over previous
//
#include <hip/hip_runtime.h>
#include <hip/hip_bf16.h>
#include <stdint.h>

typedef __attribute__((ext_vector_type(8))) short short8;
typedef __attribute__((ext_vector_type(4))) float floatx4;

// Q pre-scale: 0.125 (1/sqrt(K)) * log2(e), so exp(s/8) == exp2(q'.k)
#define QSCALE 0.18033688f

__device__ __forceinline__ unsigned short f2bf(float f) {
    unsigned int u = __float_as_uint(f);
    u += 0x7fffu + ((u >> 16) & 1u);
    return (unsigned short)(u >> 16);
}
__device__ __forceinline__ unsigned int pack2bf(float a, float b) {
    __hip_bfloat162 h = __float22bfloat162_rn(make_float2(a, b));
    return *reinterpret_cast<unsigned int*>(&h);
}

// async global->LDS, 16B per lane; LDS dst must be wave-uniform base + lane*16
__device__ __forceinline__ void async16(const void* g, void* l) {
    __builtin_amdgcn_global_load_lds(
        (const __attribute__((address_space(1))) unsigned int*)g,
        (__attribute__((address_space(3))) unsigned int*)l, 16, 0, 0);
}

// ---------------------------------------------------------------------------
// cvt: fp32 -> bf16, 8 elements/thread
// ---------------------------------------------------------------------------
__global__ __launch_bounds__(256) void cvt_bf16(const float* __restrict__ src,
                                                unsigned short* __restrict__ dst, int n8) {
    int i = blockIdx.x * 256 + threadIdx.x;
    if (i >= n8) return;
    const float4 a = ((const float4*)src)[2 * i];
    const float4 b = ((const float4*)src)[2 * i + 1];
    ushort4 lo, hi;
    lo.x = f2bf(a.x); lo.y = f2bf(a.y); lo.z = f2bf(a.z); lo.w = f2bf(a.w);
    hi.x = f2bf(b.x); hi.y = f2bf(b.y); hi.z = f2bf(b.z); hi.w = f2bf(b.w);
    ((ushort4*)dst)[2 * i] = lo;
    ((ushort4*)dst)[2 * i + 1] = hi;
}

// ---------------------------------------------------------------------------
// tcvt: fp32 [R][C] -> bf16 [C][R]  (64x64 tiles via LDS)
// ---------------------------------------------------------------------------
__global__ __launch_bounds__(256) void tcvt(const float* __restrict__ src,
                                            unsigned short* __restrict__ dst, int R, int C) {
    __shared__ unsigned short t[64][72];
    const int tid = threadIdx.x;
    const int r0 = blockIdx.y * 64, c0 = blockIdx.x * 64;
    #pragma unroll
    for (int it = 0; it < 4; it++) {
        int idx = it * 256 + tid;
        int rr = idx >> 4, cc = (idx & 15) * 4;
        float4 v = *(const float4*)(src + (size_t)(r0 + rr) * C + c0 + cc);
        t[cc + 0][rr] = f2bf(v.x);
        t[cc + 1][rr] = f2bf(v.y);
        t[cc + 2][rr] = f2bf(v.z);
        t[cc + 3][rr] = f2bf(v.w);
    }
    __syncthreads();
    #pragma unroll
    for (int it = 0; it < 2; it++) {
        int idx = it * 256 + tid;
        int cc = idx >> 3, r8 = (idx & 7) * 8;
        short8 v = *(const short8*)&t[cc][r8];
        *(short8*)(dst + (size_t)(c0 + cc) * R + r0 + r8) = v;
    }
}

// ---------------------------------------------------------------------------
// vtrans: vb[bh][2048][64] -> vbt[bh][64][2048]  (64x64 tiles via LDS)
// ---------------------------------------------------------------------------
__global__ __launch_bounds__(256) void vtrans(const unsigned short* __restrict__ vb,
                                              unsigned short* __restrict__ vbt) {
    __shared__ unsigned short t[64][72];
    const int tid = threadIdx.x;
    const int bh = blockIdx.y, m0 = blockIdx.x * 64;
    const unsigned short* src = vb + ((size_t)bh * 2048 + m0) * 64;
    unsigned short* dst = vbt + ((size_t)bh << 17) + m0;
    union { short8 v; unsigned short u[8]; } tmp;
    #pragma unroll
    for (int it = 0; it < 2; it++) {
        int idx = it * 256 + tid;
        int m = idx >> 3, c8 = (idx & 7) * 8;
        tmp.v = *(const short8*)(src + (size_t)m * 64 + c8);
        #pragma unroll
        for (int j = 0; j < 8; j++) t[c8 + j][m] = tmp.u[j];
    }
    __syncthreads();
    #pragma unroll
    for (int it = 0; it < 2; it++) {
        int idx = it * 256 + tid;
        int k = idx >> 3, c8 = (idx & 7) * 8;
        short8 v = *(const short8*)&t[k][c8];
        *(short8*)(dst + (size_t)k * 2048 + c8) = v;
    }
}

// ---------------------------------------------------------------------------
// qkv_gemm v3: R5 inner loop verbatim; epilogue rewritten. Old epilogue: 64
// scalar 2B stores/thread, ~8-op addr chain each, 4x32B segments/wave-store.
// Key fact: h = l>>7 (reshape quirk -> head is a row function), so each
// wave's 64-col slice is ONE (head, kk-block) with kk contiguous. New
// epilogue: wave-private LDS transpose (two 32-row halves in the wave's 4 KB
// slice of Smem, reused after the loop's last barrier) then short8 row
// stores -> 128B coalesced segments, 8 stores/thread/half. No extra
// __syncthreads (per-wave in-order DS pipe).
// ---------------------------------------------------------------------------
__global__ __launch_bounds__(256) void qkv_gemm(
    const unsigned short* __restrict__ A, const unsigned short* __restrict__ Bt,
    unsigned short* __restrict__ qb, unsigned short* __restrict__ kb,
    unsigned short* __restrict__ vb)
{
    __shared__ __align__(16) unsigned short Smem[2 * 128 * 32];  // As | Bs, 16 KB
    unsigned short* As = Smem;
    unsigned short* Bs = Smem + 128 * 32;
    const int tid = threadIdx.x, wave = tid >> 6, lane = tid & 63;
    const int quad = lane >> 4, lr = lane & 15;
    const int wr = wave >> 1, wc = wave & 1;
    const int bm = blockIdx.y * 128, bn = blockIdx.x * 128;
    const int lrow = lane >> 2, lcol = (lane & 3) * 8;

    floatx4 acc[4][4];
    #pragma unroll
    for (int i = 0; i < 4; i++)
        #pragma unroll
        for (int j = 0; j < 4; j++) acc[i][j] = (floatx4)0.0f;

    for (int k0 = 0; k0 < 1024; k0 += 32) {
        #pragma unroll
        for (int t = 0; t < 2; t++) {
            const int rbase = wave * 32 + t * 16;       // wave-uniform
            const int r = rbase + lrow;
            async16(A  + (size_t)(bm + r) * 1024 + k0 + lcol, &As[rbase * 32]);
            async16(Bt + (size_t)(bn + r) * 1024 + k0 + lcol, &Bs[rbase * 32]);
        }
        __syncthreads();
        short8 af[4], bfr[4];
        #pragma unroll
        for (int i = 0; i < 4; i++)
            af[i] = *(const short8*)&As[(wr * 64 + i * 16 + lr) * 32 + quad * 8];
        #pragma unroll
        for (int j = 0; j < 4; j++)
            bfr[j] = *(const short8*)&Bs[(wc * 64 + j * 16 + lr) * 32 + quad * 8];
        #pragma unroll
        for (int i = 0; i < 4; i++)
            #pragma unroll
            for (int j = 0; j < 4; j++)
                acc[i][j] = __builtin_amdgcn_mfma_f32_16x16x32_bf16(af[i], bfr[j], acc[i][j], 0, 0, 0);
        __syncthreads();
    }

    // ---- epilogue: wave-private LDS transpose + coalesced short8 stores ----
    const int part = bn >> 10;
    unsigned short* __restrict__ dstb = (part == 0) ? qb : ((part == 1) ? kb : vb);
    const float sc = (part == 0) ? QSCALE : 1.0f;
    const int dblk = ((bn & 1023) >> 6) + wc;            // d>>6, wave-uniform
    unsigned short* ep = Smem + wave * 2048;             // 32 rows x 64 cols

    #pragma unroll
    for (int half = 0; half < 2; half++) {
        #pragma unroll
        for (int il = 0; il < 2; il++) {
            const int i = half * 2 + il;
            #pragma unroll
            for (int j = 0; j < 4; j++)
                #pragma unroll
                for (int r = 0; r < 4; r++)
                    ep[(il * 16 + quad * 4 + r) * 64 + j * 16 + lr] = f2bf(acc[i][j][r] * sc);
        }
        #pragma unroll
        for (int it = 0; it < 4; it++) {
            const int slot = it * 64 + lane;
            const int rr = slot >> 3, c8 = (slot & 7) * 8;
            short8 v = *(const short8*)&ep[rr * 64 + c8];
            const int row = bm + wr * 64 + half * 32 + rr;   // global x row
            const int bidx = row >> 11, lseq = row & 2047;
            const int h = lseq >> 7;
            const int l2 = (lseq & 127) * 16 + dblk;
            *(short8*)(dstb + (((size_t)(bidx * 16 + h) * 2048 + l2) << 6) + c8) = v;
        }
        // per-wave in-order DS pipe: half-1 writes can't pass half-0 reads
    }
}

__global__ __launch_bounds__(256) void out_gemm(
    const unsigned short* __restrict__ A, const unsigned short* __restrict__ Bt,
    float* __restrict__ C)
{
    __shared__ __align__(16) unsigned short As[128 * 32];
    __shared__ __align__(16) unsigned short Bs[128 * 32];
    const int tid = threadIdx.x, wave = tid >> 6, lane = tid & 63;
    const int quad = lane >> 4, lr = lane & 15;
    const int wr = wave >> 1, wc = wave & 1;
    const int bm = blockIdx.y * 128, bn = blockIdx.x * 128;
    const int lrow = lane >> 2, lcol = (lane & 3) * 8;

    floatx4 acc[4][4];
    #pragma unroll
    for (int i = 0; i < 4; i++)
        #pragma unroll
        for (int j = 0; j < 4; j++) acc[i][j] = (floatx4)0.0f;

    for (int k0 = 0; k0 < 1024; k0 += 32) {
        #pragma unroll
        for (int t = 0; t < 2; t++) {
            const int rbase = wave * 32 + t * 16;
            const int r = rbase + lrow;
            async16(A  + (size_t)(bm + r) * 1024 + k0 + lcol, &As[rbase * 32]);
            async16(Bt + (size_t)(bn + r) * 1024 + k0 + lcol, &Bs[rbase * 32]);
        }
        __syncthreads();
        short8 af[4], bfr[4];
        #pragma unroll
        for (int i = 0; i < 4; i++)
            af[i] = *(const short8*)&As[(wr * 64 + i * 16 + lr) * 32 + quad * 8];
        #pragma unroll
        for (int j = 0; j < 4; j++)
            bfr[j] = *(const short8*)&Bs[(wc * 64 + j * 16 + lr) * 32 + quad * 8];
        #pragma unroll
        for (int i = 0; i < 4; i++)
            #pragma unroll
            for (int j = 0; j < 4; j++)
                acc[i][j] = __builtin_amdgcn_mfma_f32_16x16x32_bf16(af[i], bfr[j], acc[i][j], 0, 0, 0);
        __syncthreads();
    }
    #pragma unroll
    for (int i = 0; i < 4; i++)
        #pragma unroll
        for (int j = 0; j < 4; j++)
            #pragma unroll
            for (int r = 0; r < 4; r++) {
                int row = bm + wr * 64 + i * 16 + quad * 4 + r;
                int col = bn + wc * 64 + j * 16 + lr;
                C[(size_t)row * 1024 + col] = acc[i][j][r];
            }
}

// ---------------------------------------------------------------------------
// attn_denom v2 (R5-proven): Q/K double-buffered in LDS, staged with
// global_load_lds (un-sinkable; pre-XOR'd source involution per rule 21),
// one barrier per head. LDS 32 KB -> 5 blocks/CU.
// ---------------------------------------------------------------------------
__global__ __launch_bounds__(256, 5) void attn_denom(
    const unsigned short* __restrict__ qb, const unsigned short* __restrict__ kb,
    unsigned short* __restrict__ drpT)
{
    __shared__ __align__(16) unsigned short Qs[2][64 * 64];  // 16 KB
    __shared__ __align__(16) unsigned short Ks[2][64 * 64];  // 16 KB
    const int tid = threadIdx.x, wave = tid >> 6, lane = tid & 63;
    const int quad = lane >> 4, lr = lane & 15;
    const int e7 = lr & 7;
    const int M0 = blockIdx.x * 64, L0 = blockIdx.y * 64, b = blockIdx.z;

    const int klr = lane >> 3;
    const int ksw8 = ((lane & 7) ^ klr) * 8;
    const size_t hb0 = ((size_t)(b * 16)) << 17;
    const unsigned short* qsrc0 = qb + hb0 + (size_t)(L0 + wave * 8 + klr) * 64 + ksw8;
    const unsigned short* ksrc0 = kb + hb0 + (size_t)(M0 + wave * 8 + klr) * 64 + ksw8;

    floatx4 e[4];
    #pragma unroll
    for (int i = 0; i < 4; i++) e[i] = (floatx4)0.0f;

    async16(qsrc0,           &Qs[0][(wave * 8) * 64]);
    async16(qsrc0 + 32 * 64, &Qs[0][(32 + wave * 8) * 64]);
    async16(ksrc0,           &Ks[0][(wave * 8) * 64]);
    async16(ksrc0 + 32 * 64, &Ks[0][(32 + wave * 8) * 64]);
    __syncthreads();

    for (int h = 0; h < 16; h++) {
        const int cur = h & 1, nxt = cur ^ 1;
        if (h < 15) {
            const unsigned short* qs = qsrc0 + ((size_t)(h + 1) << 17);
            const unsigned short* ks = ksrc0 + ((size_t)(h + 1) << 17);
            async16(qs,           &Qs[nxt][(wave * 8) * 64]);
            async16(qs + 32 * 64, &Qs[nxt][(32 + wave * 8) * 64]);
            async16(ks,           &Ks[nxt][(wave * 8) * 64]);
            async16(ks + 32 * 64, &Ks[nxt][(32 + wave * 8) * 64]);
        }
        const unsigned short* qsp = &Qs[cur][0];
        const unsigned short* ksp = &Ks[cur][0];
        const int rq = wave * 16 + lr;
        short8 qf0 = *(const short8*)&qsp[rq * 64 + (quad ^ e7) * 8];
        short8 qf1 = *(const short8*)&qsp[rq * 64 + ((4 + quad) ^ e7) * 8];
        #pragma unroll
        for (int mt = 0; mt < 4; mt++) {
            const int rk = mt * 16 + lr;
            short8 kf0 = *(const short8*)&ksp[rk * 64 + (quad ^ e7) * 8];
            short8 kf1 = *(const short8*)&ksp[rk * 64 + ((4 + quad) ^ e7) * 8];
            floatx4 s = (floatx4)0.0f;
            __builtin_amdgcn_s_setprio(1);
            s = __builtin_amdgcn_mfma_f32_16x16x32_bf16(kf0, qf0, s, 0, 0, 0);
            s = __builtin_amdgcn_mfma_f32_16x16x32_bf16(kf1, qf1, s, 0, 0, 0);
            __builtin_amdgcn_s_setprio(0);
            e[mt][0] += __builtin_amdgcn_exp2f(s[0]);
            e[mt][1] += __builtin_amdgcn_exp2f(s[1]);
            e[mt][2] += __builtin_amdgcn_exp2f(s[2]);
            e[mt][3] += __builtin_amdgcn_exp2f(s[3]);
        }
        if (h < 15) __syncthreads();
    }
    #pragma unroll
    for (int mt = 0; mt < 4; mt++) {
        float r0 = __builtin_amdgcn_rcpf(e[mt][0]);
        float r1 = __builtin_amdgcn_rcpf(e[mt][1]);
        float r2 = __builtin_amdgcn_rcpf(e[mt][2]);
        float r3 = __builtin_amdgcn_rcpf(e[mt][3]);
        uint2 o;
        o.x = pack2bf(r0, r1);
        o.y = pack2bf(r2, r3);
        int mtg = (M0 >> 4) + mt;
        int ltg = (L0 >> 4) + wave;
        *(uint2*)(drpT + ((((size_t)b * 128 + mtg) * 128 + ltg) << 8) + lane * 4) = o;
    }
}

// ---------------------------------------------------------------------------
// attn_pv v6 (R5, verbatim — measured 111 us): 3-buffer K/V rotation, full
// Ps[128][64], drp reload post-S.
// ---------------------------------------------------------------------------
__global__ __launch_bounds__(256, 4) void attn_pv(
    const unsigned short* __restrict__ qb, const unsigned short* __restrict__ kb,
    const unsigned short* __restrict__ vbt, const unsigned short* __restrict__ drpT,
    unsigned short* __restrict__ cb)
{
    __shared__ __align__(16) unsigned short KV[3][64 * 64];  // 24 KB rotating K/V
    __shared__ __align__(16) unsigned short Ps[128 * 64];    // 16 KB
    const int tid = threadIdx.x, wave = tid >> 6, lane = tid & 63;
    const int quad = lane >> 4, lr = lane & 15;
    const int e7 = lr & 7;
    const int flat = blockIdx.x;
    const int swz = (flat & 7) * 128 + (flat >> 3);
    const int Lt = swz & 15;
    const int h = (swz >> 4) & 15;
    const int b = swz >> 8;
    const int L0 = Lt * 128;
    const size_t head = (size_t)(b * 16 + h);
    const unsigned short* qbase = qb + (head << 17);
    const unsigned short* kbase = kb + (head << 17);
    const unsigned short* vtb   = vbt + (head << 17);        // [64][2048]
    const unsigned short* dbase = drpT + (((size_t)b * 128 * 128 + (L0 >> 4) + wave * 2) << 8) + lane * 4;

    const int klr = lane >> 3;
    const int ksw = (lane & 7) ^ klr;
    const unsigned short* ksrc0 = kbase + (size_t)(wave * 8 + klr) * 64 + ksw * 8;
    const unsigned short* vsrc0 = vtb + (size_t)(wave * 8 + klr) * 2048 + ksw * 8;

    short8 qf[2][2];
    #pragma unroll
    for (int j = 0; j < 2; j++) {
        const unsigned short* qr = qbase + (size_t)(L0 + wave * 32 + j * 16 + lr) * 64;
        qf[j][0] = *(const short8*)(qr + quad * 8);
        qf[j][1] = *(const short8*)(qr + 32 + quad * 8);
    }

    floatx4 oacc[2][4];
    #pragma unroll
    for (int i = 0; i < 2; i++)
        #pragma unroll
        for (int j = 0; j < 4; j++) oacc[i][j] = (floatx4)0.0f;

    async16(ksrc0,             &KV[0][(wave * 8) * 64]);
    async16(ksrc0 + 32 * 64,   &KV[0][(32 + wave * 8) * 64]);
    async16(vsrc0,             &KV[1][(wave * 8) * 64]);
    async16(vsrc0 + 32 * 2048, &KV[1][(32 + wave * 8) * 64]);
    uint2 du[4][2];
    #pragma unroll
    for (int mt = 0; mt < 4; mt++)
        #pragma unroll
        for (int j = 0; j < 2; j++)
            du[mt][j] = *(const uint2*)(dbase + ((size_t)mt << 15) + (j << 8));
    __syncthreads();

    int kcur = 0, vcur = 1, sp = 2;
    for (int t = 0; t < 32; t++) {
        const int M0 = t * 64;
        if (t < 31) {
            const unsigned short* ks = ksrc0 + (size_t)(M0 + 64) * 64;
            async16(ks,           &KV[sp][(wave * 8) * 64]);
            async16(ks + 32 * 64, &KV[sp][(32 + wave * 8) * 64]);
        }
        const unsigned short* ksp = &KV[kcur][0];
        #pragma unroll
        for (int mt = 0; mt < 4; mt++) {
            const int rk = mt * 16 + lr;
            short8 kf0 = *(const short8*)&ksp[rk * 64 + (quad ^ e7) * 8];
            short8 kf1 = *(const short8*)&ksp[rk * 64 + ((4 + quad) ^ e7) * 8];
            #pragma unroll
            for (int j = 0; j < 2; j++) {
                uint2 duv = du[mt][j];
                floatx4 s = (floatx4)0.0f;
                __builtin_amdgcn_s_setprio(1);
                s = __builtin_amdgcn_mfma_f32_16x16x32_bf16(kf0, qf[j][0], s, 0, 0, 0);
                s = __builtin_amdgcn_mfma_f32_16x16x32_bf16(kf1, qf[j][1], s, 0, 0, 0);
                __builtin_amdgcn_s_setprio(0);
                float r0 = __uint_as_float(duv.x << 16);
                float r1 = __uint_as_float(duv.x & 0xffff0000u);
                float r2 = __uint_as_float(duv.y << 16);
                float r3 = __uint_as_float(duv.y & 0xffff0000u);
                float p0 = __builtin_amdgcn_exp2f(s[0]) * r0;
                float p1 = __builtin_amdgcn_exp2f(s[1]) * r1;
                float p2 = __builtin_amdgcn_exp2f(s[2]) * r2;
                float p3 = __builtin_amdgcn_exp2f(s[3]) * r3;
                uint2 o;
                o.x = pack2bf(p0, p1);
                o.y = pack2bf(p2, p3);
                const int l_loc = wave * 32 + j * 16 + lr;
                const int lb16 = mt * 2 + (quad >> 1);
                *(uint2*)&Ps[l_loc * 64 + (lb16 ^ e7) * 8 + (quad & 1) * 4] = o;
            }
        }
        if (t < 31) {
            __syncthreads();
            const unsigned short* vs = vsrc0 + (M0 + 64);
            async16(vs,             &KV[kcur][(wave * 8) * 64]);
            async16(vs + 32 * 2048, &KV[kcur][(32 + wave * 8) * 64]);
            #pragma unroll
            for (int mt = 0; mt < 4; mt++)
                #pragma unroll
                for (int j = 0; j < 2; j++)
                    du[mt][j] = *(const uint2*)(dbase + (((size_t)((t + 1) * 4 + mt)) << 15) + (j << 8));
        }
        __builtin_amdgcn_sched_barrier(0);
        const unsigned short* vsp = &KV[vcur][0];
        #pragma unroll
        for (int f = 0; f < 2; f++) {
            short8 pf[2], vf[4];
            #pragma unroll
            for (int i2 = 0; i2 < 2; i2++)
                pf[i2] = *(const short8*)&Ps[(wave * 32 + i2 * 16 + lr) * 64 + ((f * 4 + quad) ^ e7) * 8];
            #pragma unroll
            for (int j2 = 0; j2 < 4; j2++) {
                const int rv = j2 * 16 + lr;
                vf[j2] = *(const short8*)&vsp[rv * 64 + ((f * 4 + quad) ^ e7) * 8];
            }
            __builtin_amdgcn_s_setprio(1);
            #pragma unroll
            for (int j2 = 0; j2 < 4; j2++)
                #pragma unroll
                for (int i2 = 0; i2 < 2; i2++)
                    oacc[i2][j2] = __builtin_amdgcn_mfma_f32_16x16x32_bf16(
                        pf[i2], vf[j2], oacc[i2][j2], 0, 0, 0);
            __builtin_amdgcn_s_setprio(0);
        }
        if (t < 31) {
            __syncthreads();
            const int ok = kcur;
            kcur = sp;
            sp = vcur;
            vcur = ok;
        }
    }
    #pragma unroll
    for (int i2 = 0; i2 < 2; i2++)
        #pragma unroll
        for (int j2 = 0; j2 < 4; j2++)
            #pragma unroll
            for (int r = 0; r < 4; r++) {
                int row = L0 + wave * 32 + i2 * 16 + quad * 4 + r;
                int col = h * 64 + j2 * 16 + lr;
                cb[(size_t)(b * 2048 + row) * 1024 + col] = f2bf(oacc[i2][j2][r]);
            }
}

extern "C" void kernel_launch(void* const* d_in, const int* in_sizes, int n_in,
                              void* d_out, int out_size, void* d_ws, size_t ws_size,
                              hipStream_t stream) {
    const float* x    = (const float*)d_in[0];   // [4,2048,1024]
    const float* wqkv = (const float*)d_in[1];   // [1024,3072]
    const float* wo   = (const float*)d_in[2];   // [1024,1024]
    float* out = (float*)d_out;                  // [4,2048,1024] fp32

    // workspace: 100,663,296 bytes with overlays
    unsigned short* W = (unsigned short*)d_ws;
    unsigned short* qb   = W;                    // [4,16,2048,64] pre-scaled Q
    unsigned short* kb   = W + 8388608;          // [4,16,2048,64]
    unsigned short* vbt  = W + 16777216;         // [4,16,64,2048] V^T
    unsigned short* drpT = W + 25165824;         // [4][128mt][128lt][256] recip denom
    unsigned short* cb   = W + 41943040;         // [8192,1024] concat
    // overlays (lifetime-disjoint):
    unsigned short* xb    = drpT;                // bf16 x   (dead before denom)
    unsigned short* wqkvT = drpT + 8388608;      // bf16 wqkv^T [3072][1024]
    unsigned short* vb    = cb;                  // V row-major (dead before pv)
    unsigned short* woT   = drpT;                // bf16 wo^T [1024][1024] (after pv)

    cvt_bf16  <<<4096, 256, 0, stream>>>(x, xb, 1048576);
    tcvt      <<<dim3(48, 16), 256, 0, stream>>>(wqkv, wqkvT, 1024, 3072);
    qkv_gemm  <<<dim3(24, 64), 256, 0, stream>>>(xb, wqkvT, qb, kb, vb);
    vtrans    <<<dim3(32, 64), 256, 0, stream>>>(vb, vbt);
    attn_denom<<<dim3(32, 32, 4), 256, 0, stream>>>(qb, kb, drpT);
    attn_pv   <<<1024, 256, 0, stream>>>(qb, kb, vbt, drpT, cb);
    tcvt      <<<dim3(16, 16), 256, 0, stream>>>(wo, woT, 1024, 1024);
    out_gemm  <<<dim3(8, 64), 256, 0, stream>>>(cb, woT, out);
}